// Round 1
// baseline (302.861 us; speedup 1.0000x reference)
//
#include <hip/hip_runtime.h>

typedef unsigned short ushort_t;
typedef __attribute__((ext_vector_type(8))) short bf16x8;
typedef __attribute__((ext_vector_type(4))) float f32x4;
typedef __attribute__((ext_vector_type(4))) unsigned int uint4v;

// Problem constants
constexpr int BATCH = 32, CIN = 128, H = 56, W = 56, COUT = 256;
constexpr int HP = 58, WP = 58;               // padded spatial
constexpr int NPIX = BATCH * H * W;           // 100352 = 784*128
constexpr int KTOT = CIN * 9;                 // 1152
constexpr size_t WB_BYTES = (size_t)COUT * KTOT * 2;                 // 589824
constexpr size_t XP_ELEMS = (size_t)BATCH * HP * WP * CIN;           // 13,778,944
constexpr size_t XP_BYTES = XP_ELEMS * 2;                            // 27,557,888

__device__ inline ushort_t f2bf(float f) {
  union { float fl; unsigned u; } v; v.fl = f;
  unsigned u = v.u;
  return (ushort_t)((u + 0x7fffu + ((u >> 16) & 1u)) >> 16);  // RNE
}

// ---------------- pre-pass kernels ----------------

__global__ void zero_ws(uint4v* __restrict__ p, int n) {
  int i = blockIdx.x * blockDim.x + threadIdx.x;
  int stride = gridDim.x * blockDim.x;
  uint4v z = {0u, 0u, 0u, 0u};
  for (; i < n; i += stride) p[i] = z;
}

// W [256][128][3][3] f32  ->  Wb [256][9][128] bf16   (k = pos*128 + c)
__global__ void conv_w(const float* __restrict__ Ws, ushort_t* __restrict__ Wb) {
  int idx = blockIdx.x * 256 + threadIdx.x;      // < 294912
  int cout = idx / 1152;
  int r = idx - cout * 1152;
  int pos = r >> 7;
  int c = r & 127;
  Wb[idx] = f2bf(Ws[(cout * 128 + c) * 9 + pos]);
}

// x NCHW f32 -> xp [32][58][58][128] bf16, zero pad ring already memset
__global__ void xpad(const float* __restrict__ x, ushort_t* __restrict__ xp) {
  __shared__ ushort_t tile[128][57];   // [c][w], pad 57 to break bank conflicts
  int bh = blockIdx.x;                 // 0..32*56-1
  int b = bh / 56, h = bh - b * 56;
  const float* xr = x + (size_t)b * 128 * 3136 + h * 56;
  // phase 1: coalesced reads along w, write LDS[c][w] (contiguous)
  for (int base = 0; base < 7168; base += 256) {
    int idx = base + (int)threadIdx.x;
    int c = idx / 56, w = idx - c * 56;
    tile[c][w] = f2bf(xr[c * 3136 + w]);
  }
  __syncthreads();
  // phase 2: coalesced NHWC writes (consecutive c)
  ushort_t* orow = xp + ((size_t)(b * 58 + h + 1) * 58 + 1) * 128;
  for (int base = 0; base < 7168; base += 256) {
    int idx = base + (int)threadIdx.x;
    int w = idx >> 7, c = idx & 127;
    orow[w * 128 + c] = tile[c][w];
  }
}

// ---------------- main implicit-GEMM kernel ----------------
// C[cout][pix] = sum_k Wb[cout][k] * im2col[k][pix],  K-step = 64 (half channels
// of one (kh,kw)).  Block tile 128x128, 4 waves of 64x64, mfma 16x16x32 bf16.
// LDS per buffer: A [8 kblk][128 row][8] bf16 (16KB), B same (16KB); x2 dbuf = 64KB.

__global__ __launch_bounds__(256, 2) void conv_mfma(
    const ushort_t* __restrict__ Wb, const ushort_t* __restrict__ xp,
    const float* __restrict__ bias, float* __restrict__ out) {
  __shared__ ushort_t ldsA[2][8192];
  __shared__ ushort_t ldsB[2][8192];

  const int tid = threadIdx.x;
  const int lane = tid & 63;
  const int wid = tid >> 6;
  const int wm = wid >> 1, wn = wid & 1;          // 2x2 wave grid
  const int lg = lane >> 4, lr = lane & 15;
  const int tileN = blockIdx.x;                   // 0..783 (128 pixels each)
  const int blkM = blockIdx.y;                    // 0..1   (128 couts each)

  // ---- staging address precompute (constant per thread across all K-steps) ----
  const int srow = tid & 127;                     // A-row / B-pixel this thread stages
  const int hi = tid >> 7;
  const ushort_t* aBase = Wb + (size_t)(blkM * 128 + srow) * 1152;
  int pg = tileN * 128 + srow;                    // global pixel id
  int bq = pg / 3136;
  int rem = pg - bq * 3136;
  int hh = rem / 56;
  int wwp = rem - hh * 56;
  const ushort_t* bBase = xp + ((size_t)((bq * 58 + hh) * 58 + wwp)) * 128;

  const ushort_t* aPre[4];
  const ushort_t* bPre[4];
#pragma unroll
  for (int p = 0; p < 4; ++p) {
    int kc8 = (p * 2 + hi) * 8;                   // which 8-channel chunk
    aPre[p] = aBase + kc8;
    bPre[p] = bBase + kc8;
  }
  const int dOff = tid * 8;                       // lds ushort offset (lane-linear, 16B)

  f32x4 acc[4][4] = {};

  auto stage = [&](int bb, int t) {
    int pos = t >> 1;
    int half = (t & 1) << 6;                      // 0 or 64 channels
    int kh = pos / 3;
    int kw = pos - kh * 3;
    int aoff = pos * 128 + half;
    int xoff = (kh * 58 + kw) * 128 + half;
    ushort_t* dA = &ldsA[bb][0];
    ushort_t* dB = &ldsB[bb][0];
#pragma unroll
    for (int p = 0; p < 4; ++p) {
      __builtin_amdgcn_global_load_lds(
          (const __attribute__((address_space(1))) unsigned int*)(aPre[p] + aoff),
          (__attribute__((address_space(3))) unsigned int*)(dA + p * 2048 + dOff),
          16, 0, 0);
      __builtin_amdgcn_global_load_lds(
          (const __attribute__((address_space(1))) unsigned int*)(bPre[p] + xoff),
          (__attribute__((address_space(3))) unsigned int*)(dB + p * 2048 + dOff),
          16, 0, 0);
    }
  };

  auto compute = [&](int bb) {
    const ushort_t* A0 = &ldsA[bb][0];
    const ushort_t* B0 = &ldsB[bb][0];
#pragma unroll
    for (int ks = 0; ks < 2; ++ks) {
      const int kb = ks * 4 + lg;
      bf16x8 av[4], bv[4];
#pragma unroll
      for (int m = 0; m < 4; ++m)
        av[m] = *(const bf16x8*)(A0 + kb * 1024 + (wm * 64 + m * 16 + lr) * 8);
#pragma unroll
      for (int n = 0; n < 4; ++n)
        bv[n] = *(const bf16x8*)(B0 + kb * 1024 + (wn * 64 + n * 16 + lr) * 8);
#pragma unroll
      for (int m = 0; m < 4; ++m)
#pragma unroll
        for (int n = 0; n < 4; ++n)
          acc[m][n] = __builtin_amdgcn_mfma_f32_16x16x32_bf16(av[m], bv[n], acc[m][n], 0, 0, 0);
    }
  };

  stage(0, 0);
  int bb = 0;
  for (int t = 0; t < 18; ++t) {
    __syncthreads();                 // staged buf[bb] ready; prev reads of bb^1 done
    if (t < 17) stage(bb ^ 1, t + 1);
    compute(bb);
    bb ^= 1;
  }

  // ---- epilogue: D row = cout = (lane>>4)*4+r, col = pixel = lane&15 ----
  const int cb = blkM * 128 + wm * 64 + lg * 4;
  float bvv[4][4];
#pragma unroll
  for (int m = 0; m < 4; ++m)
#pragma unroll
    for (int r = 0; r < 4; ++r) bvv[m][r] = bias[cb + m * 16 + r];

#pragma unroll
  for (int n = 0; n < 4; ++n) {
    int pgo = tileN * 128 + wn * 64 + n * 16 + lr;
    int bq2 = pgo / 3136;
    int rem2 = pgo - bq2 * 3136;
    float* op = out + (size_t)bq2 * 256 * 3136 + rem2;
#pragma unroll
    for (int m = 0; m < 4; ++m)
#pragma unroll
      for (int r = 0; r < 4; ++r)
        op[(size_t)(cb + m * 16 + r) * 3136] = acc[m][n][r] + bvv[m][r];
  }
}

// ---------------- fallback (ws too small): direct fp32 conv ----------------
__global__ void conv_naive(const float* __restrict__ x, const float* __restrict__ Wt,
                           const float* __restrict__ bias, float* __restrict__ out, int total) {
  int idx = blockIdx.x * 256 + threadIdx.x;
  if (idx >= total) return;
  int w = idx % 56;
  int t1 = idx / 56;
  int h = t1 % 56;
  int t2 = t1 / 56;
  int co = t2 % 256;
  int b = t2 / 256;
  float acc = bias[co];
  for (int c = 0; c < 128; ++c)
    for (int kh = 0; kh < 3; ++kh) {
      int ih = h + kh - 1;
      if (ih < 0 || ih >= 56) continue;
      for (int kw = 0; kw < 3; ++kw) {
        int iw = w + kw - 1;
        if (iw < 0 || iw >= 56) continue;
        acc += x[((b * 128 + c) * 56 + ih) * 56 + iw] * Wt[((co * 128 + c) * 3 + kh) * 3 + kw];
      }
    }
  out[idx] = acc;
}

extern "C" void kernel_launch(void* const* d_in, const int* in_sizes, int n_in,
                              void* d_out, int out_size, void* d_ws, size_t ws_size,
                              hipStream_t stream) {
  const float* x = (const float*)d_in[0];
  const float* Wt = (const float*)d_in[1];
  const float* bias = (const float*)d_in[2];
  float* out = (float*)d_out;

  const size_t need = WB_BYTES + XP_BYTES;   // ~28.1 MB
  if (ws_size < need) {
    int total = BATCH * COUT * H * W;
    conv_naive<<<(total + 255) / 256, 256, 0, stream>>>(x, Wt, bias, out, total);
    return;
  }
  ushort_t* Wb = (ushort_t*)d_ws;
  ushort_t* xp = (ushort_t*)((char*)d_ws + WB_BYTES);

  zero_ws<<<2048, 256, 0, stream>>>((uint4v*)xp, (int)(XP_BYTES / 16));
  conv_w<<<1152, 256, 0, stream>>>(Wt, Wb);
  xpad<<<32 * 56, 256, 0, stream>>>(x, xp);
  dim3 grid(784, 2);
  conv_mfma<<<grid, 256, 0, stream>>>(Wb, xp, bias, out);
}

// Round 2
// 230.655 us; speedup vs baseline: 1.3131x; 1.3131x over previous
//
#include <hip/hip_runtime.h>

typedef unsigned short ushort_t;
typedef __attribute__((ext_vector_type(8))) short bf16x8;
typedef __attribute__((ext_vector_type(4))) float f32x4;
typedef __attribute__((ext_vector_type(4))) unsigned short ushort4v;

// Problem constants
constexpr int BATCH = 32, CIN = 128, H = 56, W = 56, COUT = 256;
constexpr int HP = 58, WP = 58;
constexpr int KTOT = CIN * 9;                                        // 1152
constexpr size_t WB_BYTES = (size_t)COUT * KTOT * 2;                 // 589824
// xp2 chunk-major: [c8=16][b=32][h=58][w=58][8ch]
constexpr int PLANE = BATCH * HP * WP;                               // 107648 chunks per c8
constexpr size_t XP_BYTES = (size_t)16 * PLANE * 8 * 2;              // 27,557,888

__device__ inline ushort_t f2bf(float f) {
  union { float fl; unsigned u; } v; v.fl = f;
  unsigned u = v.u;
  return (ushort_t)((u + 0x7fffu + ((u >> 16) & 1u)) >> 16);  // RNE
}

// ---------------- pre-pass kernels ----------------

// W [256][128][3][3] f32 -> Wb2 [t=18][kblk=8][cout=256][8] bf16
// (t = pos*2+half; cin = half*64 + kblk*8 + c)
__global__ void conv_w(const float* __restrict__ Ws, ushort_t* __restrict__ Wb2) {
  int idx = blockIdx.x * 256 + threadIdx.x;      // < 294912
  int c = idx & 7;
  int cout = (idx >> 3) & 255;
  int kb = (idx >> 11) & 7;
  int t = idx >> 14;                             // 0..17
  int pos = t >> 1, half = t & 1;
  int cin = half * 64 + kb * 8 + c;
  Wb2[idx] = f2bf(Ws[(cout * 128 + cin) * 9 + pos]);
}

// x NCHW f32 -> xp2 [c8][b][h][w][8] bf16, ring zeros written here too.
__global__ void xpad2(const float* __restrict__ x, ushort_t* __restrict__ xp2) {
  __shared__ ushort_t tile[128][58];             // [c][w_padded]
  int bh = blockIdx.x;                           // 0..32*58-1
  int b = bh / 58, h = bh - b * 58;              // h padded 0..57
  bool interior = (h >= 1 && h <= 56);
  if (interior) {
    int hIn = h - 1;
    const float4* x4 = (const float4*)x;
    {  // zero pad columns
      int ch = threadIdx.x & 127, side = threadIdx.x >> 7;
      tile[ch][side * 57] = 0;
    }
    for (int it = 0; it < 7; ++it) {
      int i = it * 256 + (int)threadIdx.x;       // < 1792 = 128ch * 14
      int ch = i / 14, q = i - ch * 14;
      float4 v = x4[(size_t)(b * 128 + ch) * 784 + hIn * 14 + q];
      int wb = 1 + q * 4;
      tile[ch][wb + 0] = f2bf(v.x);
      tile[ch][wb + 1] = f2bf(v.y);
      tile[ch][wb + 2] = f2bf(v.z);
      tile[ch][wb + 3] = f2bf(v.w);
    }
  }
  __syncthreads();
  ushort4v* o4 = (ushort4v*)xp2;
  for (int it = 0; it < 8; ++it) {
    int i = it * 256 + (int)threadIdx.x;
    if (i >= 1856) break;                        // 16 c8 * 116 ushort4
    int c8 = i / 116, r = i - c8 * 116;
    int w = r >> 1, hf = r & 1;
    ushort4v v;
    if (interior) {
      int ch = c8 * 8 + hf * 4;
      v.x = tile[ch + 0][w];
      v.y = tile[ch + 1][w];
      v.z = tile[ch + 2][w];
      v.w = tile[ch + 3][w];
    } else {
      v.x = v.y = v.z = v.w = 0;
    }
    o4[((size_t)((c8 * 32 + b) * 58 + h) * 58 + w) * 2 + hf] = v;
  }
}

// ---------------- main implicit-GEMM kernel ----------------
// C[cout][pix] = sum_k Wb[cout][k] * im2col[k][pix], K-step = 64.
// Block tile 128x128, 4 waves 64x64, mfma 16x16x32 bf16, dbuf LDS 64KB.
// All staging via global_load_lds(16B) with lane-CONTIGUOUS global spans
// (Wb2/xp2 are laid out chunk-major so LDS-linear order == global order).

__global__ __launch_bounds__(256, 2) void conv_mfma(
    const ushort_t* __restrict__ Wb2, const ushort_t* __restrict__ xp2,
    const float* __restrict__ bias, float* __restrict__ out) {
  __shared__ ushort_t ldsA[2][8192];
  __shared__ ushort_t ldsB[2][8192];

  const int tid = threadIdx.x;
  const int lane = tid & 63;
  const int wid = tid >> 6;
  const int wm = wid >> 1, wn = wid & 1;          // 2x2 wave grid
  const int lg = lane >> 4, lr = lane & 15;
  const int tileN = blockIdx.x;                   // 0..783
  const int blkM = blockIdx.y;                    // 0..1

  const int srow = tid & 127;                     // A-cout-row / B-pixel staged
  const int hi = tid >> 7;

  // A staging bases: Wb2 + kblk*2048 + blkM*1024 + srow*8   (+ t*16384 per step)
  const ushort_t* aPre[4];
  // B staging bases: xp2 + (c8lo*PLANE + pixBase)*8         (+ step offset)
  const ushort_t* bPre[4];
  {
    int pg = tileN * 128 + srow;                  // global output pixel
    int bq = pg / 3136;
    int rem = pg - bq * 3136;
    int hh = rem / 56;
    int wwp = rem - hh * 56;
    int pixBase = (bq * 58 + hh) * 58 + wwp;      // padded-space chunk index
#pragma unroll
    for (int p = 0; p < 4; ++p) {
      int kb = p * 2 + hi;
      aPre[p] = Wb2 + kb * 2048 + blkM * 1024 + srow * 8;
      bPre[p] = xp2 + ((size_t)kb * PLANE + pixBase) * 8;
    }
  }
  const int dOff = tid * 8;                       // LDS short offset (lane-linear 16B)

  f32x4 acc[4][4] = {};

  auto stage = [&](int bb, int t) {
    int pos = t >> 1;
    int kh = pos / 3;
    int kw = pos - kh * 3;
    int aoff = t * 16384;                                    // shorts
    int xoff = ((t & 1) * (8 * PLANE) + kh * 58 + kw) * 8;   // shorts
    ushort_t* dA = &ldsA[bb][0];
    ushort_t* dB = &ldsB[bb][0];
#pragma unroll
    for (int p = 0; p < 4; ++p) {
      __builtin_amdgcn_global_load_lds(
          (const __attribute__((address_space(1))) unsigned int*)(aPre[p] + aoff),
          (__attribute__((address_space(3))) unsigned int*)(dA + p * 2048 + dOff),
          16, 0, 0);
      __builtin_amdgcn_global_load_lds(
          (const __attribute__((address_space(1))) unsigned int*)(bPre[p] + xoff),
          (__attribute__((address_space(3))) unsigned int*)(dB + p * 2048 + dOff),
          16, 0, 0);
    }
  };

  auto compute = [&](int bb) {
    const ushort_t* A0 = &ldsA[bb][0];
    const ushort_t* B0 = &ldsB[bb][0];
#pragma unroll
    for (int ks = 0; ks < 2; ++ks) {
      const int kb = ks * 4 + lg;
      bf16x8 av[4], bv[4];
#pragma unroll
      for (int m = 0; m < 4; ++m)
        av[m] = *(const bf16x8*)(A0 + kb * 1024 + (wm * 64 + m * 16 + lr) * 8);
#pragma unroll
      for (int n = 0; n < 4; ++n)
        bv[n] = *(const bf16x8*)(B0 + kb * 1024 + (wn * 64 + n * 16 + lr) * 8);
#pragma unroll
      for (int m = 0; m < 4; ++m)
#pragma unroll
        for (int n = 0; n < 4; ++n)
          acc[m][n] = __builtin_amdgcn_mfma_f32_16x16x32_bf16(av[m], bv[n], acc[m][n], 0, 0, 0);
    }
  };

  stage(0, 0);
  int bb = 0;
  for (int t = 0; t < 18; ++t) {
    __syncthreads();
    if (t < 17) stage(bb ^ 1, t + 1);
    compute(bb);
    bb ^= 1;
  }

  // ---- epilogue ----
  const int cb = blkM * 128 + wm * 64 + lg * 4;
  float bvv[4][4];
#pragma unroll
  for (int m = 0; m < 4; ++m)
#pragma unroll
    for (int r = 0; r < 4; ++r) bvv[m][r] = bias[cb + m * 16 + r];

#pragma unroll
  for (int n = 0; n < 4; ++n) {
    int pgo = tileN * 128 + wn * 64 + n * 16 + lr;
    int bq2 = pgo / 3136;
    int rem2 = pgo - bq2 * 3136;
    float* op = out + (size_t)bq2 * 256 * 3136 + rem2;
#pragma unroll
    for (int m = 0; m < 4; ++m)
#pragma unroll
      for (int r = 0; r < 4; ++r)
        op[(size_t)(cb + m * 16 + r) * 3136] = acc[m][n][r] + bvv[m][r];
  }
}

// ---------------- fallback (ws too small): direct fp32 conv ----------------
__global__ void conv_naive(const float* __restrict__ x, const float* __restrict__ Wt,
                           const float* __restrict__ bias, float* __restrict__ out, int total) {
  int idx = blockIdx.x * 256 + threadIdx.x;
  if (idx >= total) return;
  int w = idx % 56;
  int t1 = idx / 56;
  int h = t1 % 56;
  int t2 = t1 / 56;
  int co = t2 % 256;
  int b = t2 / 256;
  float acc = bias[co];
  for (int c = 0; c < 128; ++c)
    for (int kh = 0; kh < 3; ++kh) {
      int ih = h + kh - 1;
      if (ih < 0 || ih >= 56) continue;
      for (int kw = 0; kw < 3; ++kw) {
        int iw = w + kw - 1;
        if (iw < 0 || iw >= 56) continue;
        acc += x[((b * 128 + c) * 56 + ih) * 56 + iw] * Wt[((co * 128 + c) * 3 + kh) * 3 + kw];
      }
    }
  out[idx] = acc;
}

extern "C" void kernel_launch(void* const* d_in, const int* in_sizes, int n_in,
                              void* d_out, int out_size, void* d_ws, size_t ws_size,
                              hipStream_t stream) {
  const float* x = (const float*)d_in[0];
  const float* Wt = (const float*)d_in[1];
  const float* bias = (const float*)d_in[2];
  float* out = (float*)d_out;

  const size_t need = WB_BYTES + XP_BYTES;   // ~28.1 MB
  if (ws_size < need) {
    int total = BATCH * COUT * H * W;
    conv_naive<<<(total + 255) / 256, 256, 0, stream>>>(x, Wt, bias, out, total);
    return;
  }
  ushort_t* Wb2 = (ushort_t*)d_ws;
  ushort_t* xp2 = (ushort_t*)((char*)d_ws + WB_BYTES);

  conv_w<<<1152, 256, 0, stream>>>(Wt, Wb2);
  xpad2<<<32 * 58, 256, 0, stream>>>(x, xp2);
  dim3 grid(784, 2);
  conv_mfma<<<grid, 256, 0, stream>>>(Wb2, xp2, bias, out);
}

// Round 4
// 213.296 us; speedup vs baseline: 1.4199x; 1.0814x over previous
//
#include <hip/hip_runtime.h>

typedef unsigned short ushort_t;
typedef __attribute__((ext_vector_type(8))) short bf16x8;
typedef __attribute__((ext_vector_type(4))) float f32x4;
typedef __attribute__((ext_vector_type(4))) unsigned short ushort4v;

// Problem constants
constexpr int BATCH = 32, CIN = 128, H = 56, W = 56, COUT = 256;
constexpr int HP = 58, WP = 58;
constexpr int KTOT = CIN * 9;                                        // 1152
constexpr size_t WB_BYTES = (size_t)COUT * KTOT * 2;                 // 589824
// xp2 chunk-major: [c8=16][b=32][h=58][w=58][8ch]
constexpr int PLANE = BATCH * HP * WP;                               // 107648 chunks per c8
constexpr size_t XP_BYTES = (size_t)16 * PLANE * 8 * 2;              // 27,557,888

__device__ inline ushort_t f2bf(float f) {
  union { float fl; unsigned u; } v; v.fl = f;
  unsigned u = v.u;
  return (ushort_t)((u + 0x7fffu + ((u >> 16) & 1u)) >> 16);  // RNE
}

// ---------------- pre-pass kernels ----------------

// W [256][128][3][3] f32 -> Wb2 [t=18][kblk=8][cout=256][8] bf16
// (t = pos*2+half; cin = half*64 + kblk*8 + c)
__global__ void conv_w(const float* __restrict__ Ws, ushort_t* __restrict__ Wb2) {
  int idx = blockIdx.x * 256 + threadIdx.x;      // < 294912
  int c = idx & 7;
  int cout = (idx >> 3) & 255;
  int kb = (idx >> 11) & 7;
  int t = idx >> 14;                             // 0..17
  int pos = t >> 1, half = t & 1;
  int cin = half * 64 + kb * 8 + c;
  Wb2[idx] = f2bf(Ws[(cout * 128 + cin) * 9 + pos]);
}

// x NCHW f32 -> xp2 [c8][b][h][w][8] bf16, ring zeros written here too.
__global__ void xpad2(const float* __restrict__ x, ushort_t* __restrict__ xp2) {
  __shared__ ushort_t tile[128][58];             // [c][w_padded]
  int bh = blockIdx.x;                           // 0..32*58-1
  int b = bh / 58, h = bh - b * 58;              // h padded 0..57
  bool interior = (h >= 1 && h <= 56);
  if (interior) {
    int hIn = h - 1;
    const float4* x4 = (const float4*)x;
    {  // zero pad columns
      int ch = threadIdx.x & 127, side = threadIdx.x >> 7;
      tile[ch][side * 57] = 0;
    }
    for (int it = 0; it < 7; ++it) {
      int i = it * 256 + (int)threadIdx.x;       // < 1792 = 128ch * 14
      int ch = i / 14, q = i - ch * 14;
      float4 v = x4[(size_t)(b * 128 + ch) * 784 + hIn * 14 + q];
      int wb = 1 + q * 4;
      tile[ch][wb + 0] = f2bf(v.x);
      tile[ch][wb + 1] = f2bf(v.y);
      tile[ch][wb + 2] = f2bf(v.z);
      tile[ch][wb + 3] = f2bf(v.w);
    }
  }
  __syncthreads();
  ushort4v* o4 = (ushort4v*)xp2;
  for (int it = 0; it < 8; ++it) {
    int i = it * 256 + (int)threadIdx.x;
    if (i >= 1856) break;                        // 16 c8 * 116 ushort4
    int c8 = i / 116, r = i - c8 * 116;
    int w = r >> 1, hf = r & 1;
    ushort4v v;
    if (interior) {
      int ch = c8 * 8 + hf * 4;
      v.x = tile[ch + 0][w];
      v.y = tile[ch + 1][w];
      v.z = tile[ch + 2][w];
      v.w = tile[ch + 3][w];
    } else {
      v.x = v.y = v.z = v.w = 0;
    }
    o4[((size_t)((c8 * 32 + b) * 58 + h) * 58 + w) * 2 + hf] = v;
  }
}

// ---------------- main implicit-GEMM kernel ----------------
// C[cout][pix] = sum_k Wb[cout][k] * im2col[k][pix].
// Tile BM=256 (ALL couts) x BN=256 pixels, BK=64, 18 K-tiles.
// 512 threads = 8 waves (2M x 4N), per-wave 128x64, mfma 16x16x32 bf16.
// LDS 128 KB: 2 buffers x (A 32KB + B 32KB), chunk-major [kb=8][row=256][8ch]
// (lane-linear staging == lane-linear fragment reads -> conflict-free, no swizzle).
// Counted-vmcnt pipeline (T3+T4): per iter, after all ds_reads of buf[p] and a
// barrier, tile t+2 is staged into buf[p]; vmcnt(8) at iter end waits only for
// tile t+1 (its 8 loads are the oldest outstanding), never draining to 0.

__global__ __launch_bounds__(512) void conv_mfma(
    const ushort_t* __restrict__ Wb2, const ushort_t* __restrict__ xp2,
    const float* __restrict__ bias, float* __restrict__ out) {
  __shared__ ushort_t ldsA[2][16384];
  __shared__ ushort_t ldsB[2][16384];

  const int tid = threadIdx.x;
  const int lane = tid & 63;
  const int wid = tid >> 6;
  const int wm = wid >> 2, wn = wid & 3;          // 2M x 4N wave grid
  const int lg = lane >> 4, lr = lane & 15;
  const int tileN = blockIdx.x;                   // 0..391 (256 pixels each)

  // ---- per-thread staging sources (constant across K-loop) ----
  const ushort_t* aSrc[4];
  const ushort_t* bSrc[4];
#pragma unroll
  for (int p = 0; p < 4; ++p) {
    int idx = p * 512 + tid;                      // 0..2047 = [kb=8][elem=256]
    aSrc[p] = Wb2 + idx * 8;
    int kb = idx >> 8, pi = idx & 255;
    int pg = tileN * 256 + pi;                    // global output pixel
    int bq = pg / 3136;
    int rem = pg - bq * 3136;
    int hh = rem / 56;
    int ww = rem - hh * 56;
    int pixBase = (bq * 58 + hh) * 58 + ww;       // padded-space chunk index
    bSrc[p] = xp2 + ((size_t)kb * PLANE + pixBase) * 8;
  }
  const int dOff = tid * 8;                       // LDS short offset per 512-chunk

  auto stage = [&](int bb, int t) {
    int pos = t >> 1;
    int kh = pos / 3;
    int kw = pos - kh * 3;
    int aoff = t * 16384;                                     // shorts
    int boff = (t & 1) * (8 * PLANE * 8) + (kh * 58 + kw) * 8; // shorts
    ushort_t* dA = &ldsA[bb][0];
    ushort_t* dB = &ldsB[bb][0];
#pragma unroll
    for (int p = 0; p < 4; ++p) {
      __builtin_amdgcn_global_load_lds(
          (const __attribute__((address_space(1))) unsigned int*)(aSrc[p] + aoff),
          (__attribute__((address_space(3))) unsigned int*)(dA + p * 4096 + dOff),
          16, 0, 0);
      __builtin_amdgcn_global_load_lds(
          (const __attribute__((address_space(1))) unsigned int*)(bSrc[p] + boff),
          (__attribute__((address_space(3))) unsigned int*)(dB + p * 4096 + dOff),
          16, 0, 0);
    }
  };

  f32x4 acc[8][4] = {};

  // ---- prologue: tiles 0 and 1 in flight ----
  stage(0, 0);
  stage(1, 1);
  asm volatile("s_waitcnt vmcnt(8)" ::: "memory");   // tile 0 landed
  __builtin_amdgcn_s_barrier();

  for (int t = 0; t < 18; ++t) {
    const int p = t & 1;
    const ushort_t* A0 = &ldsA[p][0];
    const ushort_t* B0 = &ldsB[p][0];

    // ks0 fragments + MFMA
    bf16x8 a0[8], b0[4];
    {
      const int kb = lg;                           // ks=0
#pragma unroll
      for (int m = 0; m < 8; ++m)
        a0[m] = *(const bf16x8*)(A0 + kb * 2048 + (wm * 128 + m * 16 + lr) * 8);
#pragma unroll
      for (int n = 0; n < 4; ++n)
        b0[n] = *(const bf16x8*)(B0 + kb * 2048 + (wn * 64 + n * 16 + lr) * 8);
    }
#pragma unroll
    for (int m = 0; m < 8; ++m)
#pragma unroll
      for (int n = 0; n < 4; ++n)
        acc[m][n] = __builtin_amdgcn_mfma_f32_16x16x32_bf16(a0[m], b0[n], acc[m][n], 0, 0, 0);

    // ks1 fragments
    bf16x8 a1[8], b1[4];
    {
      const int kb = 4 + lg;                       // ks=1
#pragma unroll
      for (int m = 0; m < 8; ++m)
        a1[m] = *(const bf16x8*)(A0 + kb * 2048 + (wm * 128 + m * 16 + lr) * 8);
#pragma unroll
      for (int n = 0; n < 4; ++n)
        b1[n] = *(const bf16x8*)(B0 + kb * 2048 + (wn * 64 + n * 16 + lr) * 8);
    }

    // all reads of buf[p] complete, then free it for tile t+2
    asm volatile("s_waitcnt lgkmcnt(0)" ::: "memory");
    __builtin_amdgcn_sched_barrier(0);
    __builtin_amdgcn_s_barrier();
    __builtin_amdgcn_sched_barrier(0);
    if (t < 16) stage(p, t + 2);

    __builtin_amdgcn_s_setprio(1);
#pragma unroll
    for (int m = 0; m < 8; ++m)
#pragma unroll
      for (int n = 0; n < 4; ++n)
        acc[m][n] = __builtin_amdgcn_mfma_f32_16x16x32_bf16(a1[m], b1[n], acc[m][n], 0, 0, 0);
    __builtin_amdgcn_s_setprio(0);

    // wait tile t+1 only (t+2's 8 loads stay in flight)
    if (t < 16) {
      asm volatile("s_waitcnt vmcnt(8)" ::: "memory");
    } else if (t == 16) {
      asm volatile("s_waitcnt vmcnt(0)" ::: "memory");
    }
    __builtin_amdgcn_s_barrier();
  }

  // ---- epilogue: row = cout = wm*128 + m*16 + lg*4 + r,  col = pix ----
  const int cb = wm * 128 + lg * 4;
  float bvv[8][4];
#pragma unroll
  for (int m = 0; m < 8; ++m)
#pragma unroll
    for (int r = 0; r < 4; ++r) bvv[m][r] = bias[cb + m * 16 + r];

#pragma unroll
  for (int n = 0; n < 4; ++n) {
    int pgo = tileN * 256 + wn * 64 + n * 16 + lr;
    int bq2 = pgo / 3136;
    int rem2 = pgo - bq2 * 3136;
    float* op = out + (size_t)bq2 * 256 * 3136 + rem2;
#pragma unroll
    for (int m = 0; m < 8; ++m)
#pragma unroll
      for (int r = 0; r < 4; ++r)
        op[(size_t)(cb + m * 16 + r) * 3136] = acc[m][n][r] + bvv[m][r];
  }
}

// ---------------- fallback (ws too small): direct fp32 conv ----------------
__global__ void conv_naive(const float* __restrict__ x, const float* __restrict__ Wt,
                           const float* __restrict__ bias, float* __restrict__ out, int total) {
  int idx = blockIdx.x * 256 + threadIdx.x;
  if (idx >= total) return;
  int w = idx % 56;
  int t1 = idx / 56;
  int h = t1 % 56;
  int t2 = t1 / 56;
  int co = t2 % 256;
  int b = t2 / 256;
  float acc = bias[co];
  for (int c = 0; c < 128; ++c)
    for (int kh = 0; kh < 3; ++kh) {
      int ih = h + kh - 1;
      if (ih < 0 || ih >= 56) continue;
      for (int kw = 0; kw < 3; ++kw) {
        int iw = w + kw - 1;
        if (iw < 0 || iw >= 56) continue;
        acc += x[((b * 128 + c) * 56 + ih) * 56 + iw] * Wt[((co * 128 + c) * 3 + kh) * 3 + kw];
      }
    }
  out[idx] = acc;
}

extern "C" void kernel_launch(void* const* d_in, const int* in_sizes, int n_in,
                              void* d_out, int out_size, void* d_ws, size_t ws_size,
                              hipStream_t stream) {
  const float* x = (const float*)d_in[0];
  const float* Wt = (const float*)d_in[1];
  const float* bias = (const float*)d_in[2];
  float* out = (float*)d_out;

  const size_t need = WB_BYTES + XP_BYTES;   // ~28.1 MB
  if (ws_size < need) {
    int total = BATCH * COUT * H * W;
    conv_naive<<<(total + 255) / 256, 256, 0, stream>>>(x, Wt, bias, out, total);
    return;
  }
  ushort_t* Wb2 = (ushort_t*)d_ws;
  ushort_t* xp2 = (ushort_t*)((char*)d_ws + WB_BYTES);

  conv_w<<<1152, 256, 0, stream>>>(Wt, Wb2);
  xpad2<<<32 * 58, 256, 0, stream>>>(x, xp2);
  conv_mfma<<<392, 512, 0, stream>>>(Wb2, xp2, bias, out);
}